// Round 9
// baseline (413.277 us; speedup 1.0000x reference)
//
#include <hip/hip_runtime.h>
#include <hip/hip_bf16.h>
#include <stdint.h>

// Problem constants
#define Bq 1024
#define Dq 512
#define Nq 16
#define Hq 512
#define Mq (Bq*Nq)   // 16384

typedef short v8s  __attribute__((ext_vector_type(8)));
typedef float v16f __attribute__((ext_vector_type(16)));

typedef __attribute__((address_space(3))) unsigned int as3_u32;
typedef __attribute__((address_space(1))) const unsigned int as1_u32;

__device__ __forceinline__ unsigned short f2bf(float f) {
  union { float f; unsigned u; } v; v.f = f;
  return (unsigned short)((v.u + 0x7fffu + ((v.u >> 16) & 1u)) >> 16);
}

// Xb[b*16+n][d] = bf16(x[b][d][n])
__global__ void k_transpose_x(const float* __restrict__ x, unsigned short* __restrict__ xb) {
  __shared__ float lds[Dq][Nq + 1];
  const int b = blockIdx.x;
  const float* xi = x + (size_t)b * Dq * Nq;
  const int t = threadIdx.x;
  for (int p = 0; p < (Dq*Nq)/256; ++p) {
    int i = t + p*256;
    lds[i >> 4][i & (Nq-1)] = xi[i];
  }
  __syncthreads();
  unsigned short* o = xb + (size_t)b * Nq * Dq;
  for (int p = 0; p < (Dq*Nq)/256; ++p) {
    int i = t + p*256;
    o[i] = f2bf(lds[i & (Dq-1)][i >> 9]);   // i = n*512 + d
  }
}

// One dispatch for all weight transposes: z=0 -> Ws1, z=1 -> Ws2, z>=2 -> Wc1[z-2]
// out[z][c][r] = bf16(in[z][r][c]), 512x512 each
__global__ void k_transpose_w(const float* __restrict__ Ws1, const float* __restrict__ Ws2,
                              const float* __restrict__ Wc1,
                              unsigned short* __restrict__ Ws1t, unsigned short* __restrict__ Ws2t,
                              unsigned short* __restrict__ Wc1t) {
  __shared__ float tile[32][33];
  const int z = blockIdx.z;
  const float* in;
  unsigned short* out;
  if (z == 0)      { in = Ws1; out = Ws1t; }
  else if (z == 1) { in = Ws2; out = Ws2t; }
  else             { in = Wc1 + (size_t)(z-2) * 512 * 512; out = Wc1t + (size_t)(z-2) * 512 * 512; }
  const int tx = threadIdx.x, ty = threadIdx.y;  // (32,8)
  const int c0 = blockIdx.x * 32, r0 = blockIdx.y * 32;
#pragma unroll
  for (int j = 0; j < 4; ++j)
    tile[ty + j*8][tx] = in[(size_t)(r0 + ty + j*8) * 512 + c0 + tx];
  __syncthreads();
#pragma unroll
  for (int j = 0; j < 4; ++j) {
    int c = c0 + ty + j*8;   // output row (input col)
    int r = r0 + tx;         // output col (input row)
    out[(size_t)c * 512 + r] = f2bf(tile[tx][ty + j*8]);
  }
}

// Producer/consumer 128x128 MFMA GEMM, BK=32, double-buffered LDS.
// 512 threads = 8 waves: waves 0-3 CONSUME (ds_read + MFMA; barrier drain is
// lgkmcnt-only), waves 4-7 PRODUCE (global_load_lds into the other buffer).
// RACE FIX vs R8: the compiler does NOT emit `s_waitcnt vmcnt(0)` before
// s_barrier in the producer (it never reads the loaded data, so no visible
// dependency) — consumers could read an in-flight buffer. Explicit
// `s_waitcnt vmcnt(0)` before each producer barrier closes it; the drain sits
// in producer waves only, issued a full compute-interval after the loads.
// XOR swizzle: 16B chunk c of row r at slot c ^ ((r>>1)&3) (0-conflict, R2).
// Fragment chunk for k-half kh: c = kh*2 + (lane>>5).
// Consumer waves 2x2, wave tile 64x64 (2mi x 2ni of v_mfma_f32_32x32x16_bf16).
// MODE 0: out = lrelu(A@B+bias) bf16, rows permuted to m=(r&15)*1024+(r>>4) if permute.
// MODE 1: per-head z: atomicAdd FL[m][z] += sum_cols lrelu(A@B+bc1[z])*Wc2[z][col].
template<int MODE>
__global__ __launch_bounds__(512, 4)
void k_gemm(const unsigned short* __restrict__ A,
            const unsigned short* __restrict__ Bt,
            const float* __restrict__ bias,
            void* __restrict__ out_,
            const float* __restrict__ w2,
            int permute) {
  constexpr int BM = 128, BN = 128, BK = 32, KD = 512, NKT = KD / BK;
  __shared__ __align__(16) unsigned short As[2][BM][BK];   // 2 x 8 KB
  __shared__ __align__(16) unsigned short Bs[2][BN][BK];   // 2 x 8 KB

  const int t = threadIdx.x;
  const int wave = t >> 6, lane = t & 63;
  const int bm = blockIdx.x * BM, bn = blockIdx.y * BN;
  const int z = blockIdx.z;
  const unsigned short* Bz = Bt + (size_t)z * KD * 512;
  const float* biasz = bias + (size_t)z * 512;

  if (wave >= 4) {
    // ---- producer waves ----
    const int pw = wave - 4;
    const int lrow = lane >> 2, lslot = lane & 3;
    auto stage = [&](int buf, int kt) {
#pragma unroll
      for (int i = pw; i < 16; i += 4) {     // 16 groups of 16 rows (A:0-7, B:8-15)
        const bool isA = (i < 8);
        const int r0 = (isA ? i : i - 8) * 16;
        const int row = r0 + lrow;
        const int cg = lslot ^ ((row >> 1) & 3);
        const unsigned short* g = isA ? &A [(size_t)(bm + row) * KD + kt*BK + cg*8]
                                      : &Bz[(size_t)(bn + row) * KD + kt*BK + cg*8];
        as3_u32* d = isA ? (as3_u32*)&As[buf][r0][0] : (as3_u32*)&Bs[buf][r0][0];
        __builtin_amdgcn_global_load_lds((as1_u32*)g, d, 16, 0, 0);
      }
    };
    stage(0, 0);
    asm volatile("s_waitcnt vmcnt(0)" ::: "memory");
    __syncthreads();                          // buf0 ready
    for (int kt = 0; kt < NKT; ++kt) {
      if (kt + 1 < NKT) stage((kt + 1) & 1, kt + 1);
      asm volatile("s_waitcnt vmcnt(0)" ::: "memory");  // buf kt+1 complete...
      __syncthreads();                        // ...before consumers cross into it
    }
    return;
  }

  // ---- consumer waves ----
  const int wrm = wave >> 1, wrn = wave & 1;
  const int l32 = lane & 31, kh0 = lane >> 5;
  v16f acc[2][2] = {};

  __syncthreads();                            // buf0 ready
  for (int kt = 0; kt < NKT; ++kt) {
    const int cur = kt & 1;
#pragma unroll
    for (int kh = 0; kh < 2; ++kh) {
      const int c = kh*2 + kh0;
      v8s af[2], bf[2];
#pragma unroll
      for (int mi = 0; mi < 2; ++mi) {
        int ra = wrm*64 + mi*32 + l32;
        af[mi] = *(const v8s*)&As[cur][ra][(c ^ ((ra >> 1) & 3)) * 8];
      }
#pragma unroll
      for (int ni = 0; ni < 2; ++ni) {
        int rb = wrn*64 + ni*32 + l32;
        bf[ni] = *(const v8s*)&Bs[cur][rb][(c ^ ((rb >> 1) & 3)) * 8];
      }
#pragma unroll
      for (int mi = 0; mi < 2; ++mi)
#pragma unroll
        for (int ni = 0; ni < 2; ++ni)
          acc[mi][ni] = __builtin_amdgcn_mfma_f32_32x32x16_bf16(af[mi], bf[ni], acc[mi][ni], 0, 0, 0);
    }
    __syncthreads();                          // lgkmcnt-only drain for consumers
  }

  if (MODE == 0) {
    unsigned short* O = (unsigned short*)out_;
#pragma unroll
    for (int mi = 0; mi < 2; ++mi) {
#pragma unroll
      for (int ni = 0; ni < 2; ++ni) {
        int col = bn + wrn*64 + ni*32 + l32;
        float bcol = biasz[col];
#pragma unroll
        for (int reg = 0; reg < 16; ++reg) {
          int rl = (reg & 3) + 8*(reg >> 2) + 4*kh0;
          int grow = bm + wrm*64 + mi*32 + rl;
          int orow = permute ? ((grow & 15) * Bq + (grow >> 4)) : grow;
          float v = acc[mi][ni][reg] + bcol;
          v = v >= 0.f ? v : 0.1f * v;
          O[(size_t)orow * 512 + col] = f2bf(v);
        }
      }
    }
  } else {
    float* FL = (float*)out_;             // [Mq][Nq]
    const float* w2z = w2 + (size_t)z * 512;
#pragma unroll
    for (int mi = 0; mi < 2; ++mi) {
#pragma unroll
      for (int reg = 0; reg < 16; ++reg) {
        int rl = (reg & 3) + 8*(reg >> 2) + 4*kh0;
        float s = 0.f;
#pragma unroll
        for (int ni = 0; ni < 2; ++ni) {
          int col = bn + wrn*64 + ni*32 + l32;
          float v = acc[mi][ni][reg] + biasz[col];
          v = v >= 0.f ? v : 0.1f * v;
          s += v * w2z[col];
        }
        // reduce 32 cols within each 32-lane half (rows differ across halves)
#pragma unroll
        for (int off = 1; off < 32; off <<= 1)
          s += __shfl_xor(s, off, 64);
        if (l32 == 0) {
          int grow = bm + wrm*64 + mi*32 + rl;
          atomicAdd(&FL[(size_t)grow * Nq + z], s);
        }
      }
    }
  }
}

// full_out[m][n] = FL[m][n] + bc2[n]; out[b][n] = sigmoid(full_out[n*B+b][n])
__global__ void k_final(const float* __restrict__ fl, const float* __restrict__ bc2,
                        float* __restrict__ out) {
  int i = blockIdx.x * 256 + threadIdx.x;   // i over Mq*Nq
  int m = i >> 4, n = i & 15;
  float v = fl[i] + bc2[n];
  out[Mq + i] = v;                           // full_out, offset by |out| = 16384
  if (n == (m >> 10)) {                      // diagonal: m = n*B + b
    int b = m & (Bq - 1);
    out[b * Nq + n] = 1.f / (1.f + __expf(-v));
  }
}

extern "C" void kernel_launch(void* const* d_in, const int* in_sizes, int n_in,
                              void* d_out, int out_size, void* d_ws, size_t ws_size,
                              hipStream_t stream) {
  (void)in_sizes; (void)n_in; (void)out_size; (void)ws_size;
  const float* x   = (const float*)d_in[0];
  const float* Ws1 = (const float*)d_in[1];
  const float* bs1 = (const float*)d_in[2];
  const float* Ws2 = (const float*)d_in[3];
  const float* bs2 = (const float*)d_in[4];
  const float* Wc1 = (const float*)d_in[5];
  const float* bc1 = (const float*)d_in[6];
  const float* Wc2 = (const float*)d_in[7];
  const float* bc2 = (const float*)d_in[8];

  char* ws = (char*)d_ws;
  unsigned short* Xb   = (unsigned short*)(ws);                          // 16 MB
  unsigned short* Hbuf = (unsigned short*)(ws + (size_t)16*1024*1024);   // 16 MB
  unsigned short* Sm   = (unsigned short*)(ws + (size_t)32*1024*1024);   // 16 MB
  unsigned short* Ws1t = (unsigned short*)(ws + (size_t)48*1024*1024);   // 512 KB
  unsigned short* Ws2t = (unsigned short*)(ws + (size_t)48*1024*1024 + 512*1024);
  unsigned short* Wc1t = (unsigned short*)(ws + (size_t)49*1024*1024);   // 8 MB
  float*          FL   = (float*)         (ws + (size_t)57*1024*1024);   // 1 MB

  hipMemsetAsync(FL, 0, (size_t)Mq * Nq * sizeof(float), stream);

  k_transpose_x<<<Bq, 256, 0, stream>>>(x, Xb);
  k_transpose_w<<<dim3(16,16,18), dim3(32,8), 0, stream>>>(Ws1, Ws2, Wc1, Ws1t, Ws2t, Wc1t);

  // shared MLP: H = lrelu(Xb@Ws1+bs1); Sm = lrelu(H@Ws2+bs2) in m = n*B+b row order
  k_gemm<0><<<dim3(128,4,1), 512, 0, stream>>>(Xb,   Ws1t, bs1, Hbuf, nullptr, 0);
  k_gemm<0><<<dim3(128,4,1), 512, 0, stream>>>(Hbuf, Ws2t, bs2, Sm,   nullptr, 1);
  // fused per-head GEMM + H-reduction into FL (producer/consumer waves)
  k_gemm<1><<<dim3(128,4,16), 512, 0, stream>>>(Sm, Wc1t, bc1, FL, Wc2, 0);

  k_final<<<(Mq*Nq)/256, 256, 0, stream>>>(FL, bc2, (float*)d_out);
}

// Round 10
// 329.449 us; speedup vs baseline: 1.2545x; 1.2545x over previous
//
#include <hip/hip_runtime.h>
#include <hip/hip_bf16.h>
#include <stdint.h>

// Problem constants
#define Bq 1024
#define Dq 512
#define Nq 16
#define Hq 512
#define Mq (Bq*Nq)   // 16384

typedef short v8s __attribute__((ext_vector_type(8)));
typedef float v4f __attribute__((ext_vector_type(4)));

typedef __attribute__((address_space(3))) unsigned int as3_u32;
typedef __attribute__((address_space(1))) const unsigned int as1_u32;

__device__ __forceinline__ unsigned short f2bf(float f) {
  union { float f; unsigned u; } v; v.f = f;
  return (unsigned short)((v.u + 0x7fffu + ((v.u >> 16) & 1u)) >> 16);
}

// Xb[b*16+n][d] = bf16(x[b][d][n])
__global__ void k_transpose_x(const float* __restrict__ x, unsigned short* __restrict__ xb) {
  __shared__ float lds[Dq][Nq + 1];
  const int b = blockIdx.x;
  const float* xi = x + (size_t)b * Dq * Nq;
  const int t = threadIdx.x;
  for (int p = 0; p < (Dq*Nq)/256; ++p) {
    int i = t + p*256;
    lds[i >> 4][i & (Nq-1)] = xi[i];
  }
  __syncthreads();
  unsigned short* o = xb + (size_t)b * Nq * Dq;
  for (int p = 0; p < (Dq*Nq)/256; ++p) {
    int i = t + p*256;
    o[i] = f2bf(lds[i & (Dq-1)][i >> 9]);   // i = n*512 + d
  }
}

// One dispatch for all weight transposes: z=0 -> Ws1, z=1 -> Ws2, z>=2 -> Wc1[z-2]
// out[z][c][r] = bf16(in[z][r][c]), 512x512 each
__global__ void k_transpose_w(const float* __restrict__ Ws1, const float* __restrict__ Ws2,
                              const float* __restrict__ Wc1,
                              unsigned short* __restrict__ Ws1t, unsigned short* __restrict__ Ws2t,
                              unsigned short* __restrict__ Wc1t) {
  __shared__ float tile[32][33];
  const int z = blockIdx.z;
  const float* in;
  unsigned short* out;
  if (z == 0)      { in = Ws1; out = Ws1t; }
  else if (z == 1) { in = Ws2; out = Ws2t; }
  else             { in = Wc1 + (size_t)(z-2) * 512 * 512; out = Wc1t + (size_t)(z-2) * 512 * 512; }
  const int tx = threadIdx.x, ty = threadIdx.y;  // (32,8)
  const int c0 = blockIdx.x * 32, r0 = blockIdx.y * 32;
#pragma unroll
  for (int j = 0; j < 4; ++j)
    tile[ty + j*8][tx] = in[(size_t)(r0 + ty + j*8) * 512 + c0 + tx];
  __syncthreads();
#pragma unroll
  for (int j = 0; j < 4; ++j) {
    int c = c0 + ty + j*8;   // output row (input col)
    int r = r0 + tx;         // output col (input row)
    out[(size_t)c * 512 + r] = f2bf(tile[tx][ty + j*8]);
  }
}

// 128x128 tile MFMA GEMM (16x16x32 bf16), BK=32, 2-barrier K-loop — the R2 kernel
// verbatim (best measured: 224 us GEMM3, 0 bank conflicts, VGPR 76, ~2.5 blk/CU).
// Staging via global_load_lds w=16; XOR swizzle: 16B chunk c of row r at slot
// c ^ ((r>>1)&3); fragment chunk = quad ^ ((r>>1)&3).
// SWIZ=1 (GEMM3): 1-D grid 8192, XCD-aware decode — xcd = L%8 owns bm-slice
// (xcd*16 + s%16)*128, so each XCD's L2 holds a fixed 2 MB slice of A for the
// whole dispatch + ~1 MB rolling B window (z slow) -> per-XCD WS fits 4 MB L2.
// Cuts L3->L2 streaming ~6x vs row-major dispatch (the R2-R9 shared wall).
// MODE 0: out = lrelu(A@B+bias) bf16, rows permuted to m=(r&15)*1024+(r>>4) if permute.
// MODE 1: per-head z: atomicAdd FL[m][z] += sum_cols lrelu(A@B+bc1[z])*Wc2[z][col].
template<int MODE, int SWIZ>
__global__ __launch_bounds__(256)
void k_gemm(const unsigned short* __restrict__ A,
            const unsigned short* __restrict__ Bt,
            const float* __restrict__ bias,
            void* __restrict__ out_,
            const float* __restrict__ w2,
            int permute) {
  constexpr int BM = 128, BN = 128, BK = 32, KD = 512;
  __shared__ __align__(16) unsigned short As[BM][BK];  // 8 KB
  __shared__ __align__(16) unsigned short Bs[BN][BK];  // 8 KB

  const int t = threadIdx.x;
  const int wave = t >> 6, lane = t & 63;
  const int wr = wave >> 1, wc = wave & 1;
  const int quad = lane >> 4, l16 = lane & 15;

  int bm, bn, z;
  if (SWIZ) {
    const int L = blockIdx.x;            // 0..8191
    const int xcd = L & 7, s = L >> 3;   // round-robin XCD by linear id
    bm = (xcd * 16 + (s & 15)) * BM;     // fixed per-XCD A slice (2 MB)
    const int yz = s >> 4;               // 0..63
    bn = (yz & 3) * BN;
    z = yz >> 2;                         // slowest: rolling 1 MB B window
  } else {
    bm = blockIdx.x * BM; bn = blockIdx.y * BN; z = blockIdx.z;
  }

  const unsigned short* Bz = Bt + (size_t)z * KD * 512;
  const float* biasz = bias + (size_t)z * 512;

  const int srow0 = wave * 32;
  const int lrow = lane >> 2;
  const int lslot = lane & 3;

  v4f acc[4][4] = {};

  for (int kt = 0; kt < KD / BK; ++kt) {
#pragma unroll
    for (int p = 0; p < 2; ++p) {
      int r0 = srow0 + p * 16;
      int row = r0 + lrow;
      int cg = lslot ^ ((row >> 1) & 3);       // swizzled global chunk
      const unsigned short* ga = &A [(size_t)(bm + row) * KD + kt*BK + cg*8];
      const unsigned short* gb = &Bz[(size_t)(bn + row) * KD + kt*BK + cg*8];
      __builtin_amdgcn_global_load_lds((as1_u32*)ga, (as3_u32*)&As[r0][0], 16, 0, 0);
      __builtin_amdgcn_global_load_lds((as1_u32*)gb, (as3_u32*)&Bs[r0][0], 16, 0, 0);
    }
    __syncthreads();
    v8s af[4], bf[4];
#pragma unroll
    for (int mi = 0; mi < 4; ++mi) {
      int ra = wr*64 + mi*16 + l16;
      af[mi] = *(const v8s*)&As[ra][(quad ^ ((ra >> 1) & 3)) * 8];
    }
#pragma unroll
    for (int ni = 0; ni < 4; ++ni) {
      int rb = wc*64 + ni*16 + l16;
      bf[ni] = *(const v8s*)&Bs[rb][(quad ^ ((rb >> 1) & 3)) * 8];
    }
#pragma unroll
    for (int mi = 0; mi < 4; ++mi)
#pragma unroll
      for (int ni = 0; ni < 4; ++ni)
        acc[mi][ni] = __builtin_amdgcn_mfma_f32_16x16x32_bf16(af[mi], bf[ni], acc[mi][ni], 0, 0, 0);
    __syncthreads();
  }

  if (MODE == 0) {
    unsigned short* O = (unsigned short*)out_;
#pragma unroll
    for (int mi = 0; mi < 4; ++mi) {
#pragma unroll
      for (int r = 0; r < 4; ++r) {
        int grow = bm + wr*64 + mi*16 + quad*4 + r;
        int orow = permute ? ((grow & 15) * Bq + (grow >> 4)) : grow;
#pragma unroll
        for (int ni = 0; ni < 4; ++ni) {
          int col = bn + wc*64 + ni*16 + l16;
          float v = acc[mi][ni][r] + biasz[col];
          v = v >= 0.f ? v : 0.1f * v;
          O[(size_t)orow * 512 + col] = f2bf(v);
        }
      }
    }
  } else {
    float* FL = (float*)out_;             // [Mq][Nq]
    const float* w2z = w2 + (size_t)z * 512;
#pragma unroll
    for (int mi = 0; mi < 4; ++mi) {
#pragma unroll
      for (int r = 0; r < 4; ++r) {
        float s = 0.f;
#pragma unroll
        for (int ni = 0; ni < 4; ++ni) {
          int col = bn + wc*64 + ni*16 + l16;
          float v = acc[mi][ni][r] + biasz[col];
          v = v >= 0.f ? v : 0.1f * v;
          s += v * w2z[col];
        }
        // reduce the 16 lanes of this quad (same output row)
#pragma unroll
        for (int off = 1; off < 16; off <<= 1)
          s += __shfl_xor(s, off, 64);
        if (l16 == 0) {
          int grow = bm + wr*64 + mi*16 + quad*4 + r;
          atomicAdd(&FL[(size_t)grow * Nq + z], s);
        }
      }
    }
  }
}

// full_out[m][n] = FL[m][n] + bc2[n]; out[b][n] = sigmoid(full_out[n*B+b][n])
__global__ void k_final(const float* __restrict__ fl, const float* __restrict__ bc2,
                        float* __restrict__ out) {
  int i = blockIdx.x * 256 + threadIdx.x;   // i over Mq*Nq
  int m = i >> 4, n = i & 15;
  float v = fl[i] + bc2[n];
  out[Mq + i] = v;                           // full_out, offset by |out| = 16384
  if (n == (m >> 10)) {                      // diagonal: m = n*B + b
    int b = m & (Bq - 1);
    out[b * Nq + n] = 1.f / (1.f + __expf(-v));
  }
}

extern "C" void kernel_launch(void* const* d_in, const int* in_sizes, int n_in,
                              void* d_out, int out_size, void* d_ws, size_t ws_size,
                              hipStream_t stream) {
  (void)in_sizes; (void)n_in; (void)out_size; (void)ws_size;
  const float* x   = (const float*)d_in[0];
  const float* Ws1 = (const float*)d_in[1];
  const float* bs1 = (const float*)d_in[2];
  const float* Ws2 = (const float*)d_in[3];
  const float* bs2 = (const float*)d_in[4];
  const float* Wc1 = (const float*)d_in[5];
  const float* bc1 = (const float*)d_in[6];
  const float* Wc2 = (const float*)d_in[7];
  const float* bc2 = (const float*)d_in[8];

  char* ws = (char*)d_ws;
  unsigned short* Xb   = (unsigned short*)(ws);                          // 16 MB
  unsigned short* Hbuf = (unsigned short*)(ws + (size_t)16*1024*1024);   // 16 MB
  unsigned short* Sm   = (unsigned short*)(ws + (size_t)32*1024*1024);   // 16 MB
  unsigned short* Ws1t = (unsigned short*)(ws + (size_t)48*1024*1024);   // 512 KB
  unsigned short* Ws2t = (unsigned short*)(ws + (size_t)48*1024*1024 + 512*1024);
  unsigned short* Wc1t = (unsigned short*)(ws + (size_t)49*1024*1024);   // 8 MB
  float*          FL   = (float*)         (ws + (size_t)57*1024*1024);   // 1 MB

  hipMemsetAsync(FL, 0, (size_t)Mq * Nq * sizeof(float), stream);

  k_transpose_x<<<Bq, 256, 0, stream>>>(x, Xb);
  k_transpose_w<<<dim3(16,16,18), dim3(32,8), 0, stream>>>(Ws1, Ws2, Wc1, Ws1t, Ws2t, Wc1t);

  // shared MLP: H = lrelu(Xb@Ws1+bs1); Sm = lrelu(H@Ws2+bs2) in m = n*B+b row order
  k_gemm<0,0><<<dim3(128,4,1), 256, 0, stream>>>(Xb,   Ws1t, bs1, Hbuf, nullptr, 0);
  k_gemm<0,0><<<dim3(128,4,1), 256, 0, stream>>>(Hbuf, Ws2t, bs2, Sm,   nullptr, 1);
  // fused per-head GEMM + H-reduction into FL (XCD-swizzled 1-D grid)
  k_gemm<1,1><<<dim3(8192,1,1), 256, 0, stream>>>(Sm, Wc1t, bc1, FL, Wc2, 0);

  k_final<<<(Mq*Nq)/256, 256, 0, stream>>>(FL, bc2, (float*)d_out);
}